// Round 6
// baseline (167.109 us; speedup 1.0000x reference)
//
#include <hip/hip_runtime.h>
#include <hip/hip_bf16.h>
#include <stdint.h>

typedef __hip_bfloat16 bf16_t;
typedef __attribute__((ext_vector_type(8))) __bf16 bf16x8;
typedef __attribute__((ext_vector_type(4))) float f32x4;
typedef __attribute__((ext_vector_type(8))) unsigned short ushort8;
typedef __attribute__((ext_vector_type(2))) unsigned long long u64x2;

#define BM 256
#define BN 256
#define BK 64
#define THREADS 512
#define OPBYTES 32768   // one operand per buf: 256 rows x 128 B
#define BUFBYTES 65536  // A + B
#define LDS_TOTAL 131072

// ---------------- fused quantize: q = rint(v*100)/100, cast to bf16 ----------------
__global__ __launch_bounds__(256) void quant2_bf16_kernel(
    const float* __restrict__ x, const float* __restrict__ w,
    bf16_t* __restrict__ q, long axn8, long totn8) {
  long idx = (long)blockIdx.x * blockDim.x + threadIdx.x;
  long stride = (long)gridDim.x * blockDim.x;
  for (long i = idx; i < totn8; i += stride) {
    const float* src = (i < axn8) ? (x + i * 8) : (w + (i - axn8) * 8);
    const float4* p = reinterpret_cast<const float4*>(src);
    float4 v0 = p[0];
    float4 v1 = p[1];
    float vv[8] = {v0.x, v0.y, v0.z, v0.w, v1.x, v1.y, v1.z, v1.w};
    ushort8 r;
#pragma unroll
    for (int j = 0; j < 8; ++j) {
      float qq = rintf(vv[j] * 100.0f) / 100.0f;  // half-to-even, matches jnp.round
      __hip_bfloat16 h = __float2bfloat16(qq);
      r[j] = __builtin_bit_cast(unsigned short, h);
    }
    u64x2 u = __builtin_bit_cast(u64x2, r);
    unsigned long long* dst = reinterpret_cast<unsigned long long*>(q + i * 8);
    __hip_atomic_store(dst + 0, u[0], __ATOMIC_RELAXED, __HIP_MEMORY_SCOPE_AGENT);
    __hip_atomic_store(dst + 1, u[1], __ATOMIC_RELAXED, __HIP_MEMORY_SCOPE_AGENT);
  }
}

// ---------------- fallback ----------------
__global__ void naive_kernel(const float* __restrict__ x, const float* __restrict__ W,
                             const float* __restrict__ b, float* __restrict__ out,
                             int M, int N, int K) {
  int o = blockIdx.x * blockDim.x + threadIdx.x;
  int m = blockIdx.y;
  if (o >= N || m >= M) return;
  float s = 0.f;
  for (int k = 0; k < K; ++k) {
    float qx = rintf(x[(size_t)m * K + k] * 100.f) / 100.f;
    float qw = rintf(W[(size_t)o * K + k] * 100.f) / 100.f;
    s += qx * qw;
  }
  float v = s + b[o];
  __hip_atomic_store(out + (size_t)m * N + o, v, __ATOMIC_RELAXED,
                     __HIP_MEMORY_SCOPE_AGENT);
}

__device__ __forceinline__ void gload_lds16(const bf16_t* g, const char* l) {
  __builtin_amdgcn_global_load_lds(
      (const __attribute__((address_space(1))) unsigned int*)g,
      (__attribute__((address_space(3))) unsigned int*)l, 16, 0, 0);
}

#define BARRIER()                               \
  do {                                          \
    asm volatile("" ::: "memory");              \
    __builtin_amdgcn_s_barrier();               \
    asm volatile("" ::: "memory");              \
  } while (0)
#define LGKM0() asm volatile("s_waitcnt lgkmcnt(0)" ::: "memory")
#define VM4() asm volatile("s_waitcnt vmcnt(4)" ::: "memory")
#define VM0() asm volatile("s_waitcnt vmcnt(0)" ::: "memory")

// ---------------- bf16 GEMM, B^T input: C[m][n] = sum_k A[m][k]*B[n][k] + bias[n]
// 8-phase template (T3+T4+T5): BM=BN=256, BK=64, 8 waves (2x4; each 128x64 out).
// 2 LDS K-tile buffers; per phase: {ds_read quadrant frags | stage 1 half-tile
// (2 global_load_lds) -> barrier -> lgkmcnt(0) -> setprio(1) -> 16 MFMA ->
// setprio(0) -> barrier}; counted vmcnt(4) only at phases 4 and 8.
//
// vmcnt ledger (per wave; each STAGE = 2 loads, oldest-first retirement):
//   prologue: 12 issued, VM4 retires buf0's 8 -> 4 in flight (b1.B0,b1.B1).
//   steady iter: ph1 +b1.A0, ph2 +b1.A1, ph3 +b0.B0', ph4 +b0.B1' -> 12;
//     ph4 VM4 retires 8 oldest (ALL of buf1 tile t1) -> b0.B' x2 remain.
//     ph5 +b0.A0', ph6 +b0.A1', ph7 +b1.B0'', ph8 +b1.B1'' -> 12;
//     ph8 VM4 retires 8 oldest (ALL of buf0 tile t0+2) -> b1.B'' x2 remain.
//   LAST iteration is PEELED: only ph1/ph2 stage (b1.A halves); ph4 does a
//   full vmcnt(0) drain. (Round-5 race: with the shared loop body, ph4's
//   VM4 left b1.A0/A1 in flight while ph5/ph7 ds_read them -> intermittent
//   divergence under graph replay. Ledger must hold at boundaries, not just
//   steady state.)
//
// WAR safety: every STAGE overwrites a half whose last ds_read completed
// (LGKM0) >= 2 barriers earlier. LDS swizzle: 128B rows, stored slot =
// slot ^ (row&7) (involution; 2 lanes/bank on ds_read_b128 = free per m136).
// global_load_lds dest is linear (base+lane*16); swizzle applied on the
// global SOURCE address (rule #21).
__global__ __launch_bounds__(THREADS, 2) void gemm_bt_bf16(
    const bf16_t* __restrict__ A,   // [M][K]
    const bf16_t* __restrict__ B,   // [N][K]
    const float* __restrict__ bias, // [N]
    float* __restrict__ C,          // [M][N]
    int M, int N, int K) {
  extern __shared__ char lds[];

  const int tid = threadIdx.x;
  const int lane = tid & 63;
  const int wave = tid >> 6;  // 0..7
  const int wm = wave >> 2;   // 0..1 -> output rows wm*128..+128
  const int wn = wave & 3;    // 0..3 -> output cols wn*64..+64
  const int lr = lane & 15;
  const int lg = lane >> 4;

  // XCD-aware bijective swizzle (nwg % 8 == 0 guaranteed by tiled_ok)
  int nbn = N / BN;
  int nwg = gridDim.x;
  int bid = blockIdx.x;
  int swz = bid;
  if ((nwg & 7) == 0) {
    int cpx = nwg >> 3;
    swz = (bid & 7) * cpx + (bid >> 3);
  }
  const int brow = (swz / nbn) * BM;
  const int bcol = (swz % nbn) * BN;

  // ds_read byte offsets within an operand region (kk=0; kk=1 is ^64: slot bit2)
  int aoffs[8], boffs[4];
#pragma unroll
  for (int m = 0; m < 8; ++m) {
    int r = wm * 128 + m * 16 + lr;
    aoffs[m] = r * 128 + (((lg) ^ (r & 7)) << 4);
  }
#pragma unroll
  for (int n = 0; n < 4; ++n) {
    int r = wn * 64 + n * 16 + lr;
    boffs[n] = r * 128 + (((lg) ^ (r & 7)) << 4);
  }

  f32x4 acc[8][4];
#pragma unroll
  for (int m = 0; m < 8; ++m)
#pragma unroll
    for (int n = 0; n < 4; ++n) acc[m][n] = (f32x4){0.f, 0.f, 0.f, 0.f};

  const int nt = K / BK;

  // Stage one half-tile (16 KiB = 2 x 512thr x 16B). Linear LDS dest
  // (= base + lane*16 within each wave); inverse swizzle on global source.
  auto STAGE_A = [&](int h, int kt, int q) {
#pragma unroll
    for (int i = 0; i < 2; ++i) {
      int row = h * 128 + i * 64 + (tid >> 3);
      int L = q * BUFBYTES + row * 128 + ((tid & 7) << 4);
      int slot = (tid & 7) ^ (row & 7);
      gload_lds16(A + (size_t)(brow + row) * K + (size_t)kt * 64 + slot * 8,
                  lds + L);
    }
  };
  auto STAGE_B = [&](int h, int kt, int q) {
#pragma unroll
    for (int i = 0; i < 2; ++i) {
      int row = h * 128 + i * 64 + (tid >> 3);
      int L = q * BUFBYTES + OPBYTES + row * 128 + ((tid & 7) << 4);
      int slot = (tid & 7) ^ (row & 7);
      gload_lds16(B + (size_t)(bcol + row) * K + (size_t)kt * 64 + slot * 8,
                  lds + L);
    }
  };

  bf16x8 aq[8], blo[4], bhi[4];  // A quadrant [mm][kk]; B quadrants [nn][kk]
  auto READ_A = [&](int q, int mh) {
#pragma unroll
    for (int mm = 0; mm < 4; ++mm) {
      int off = q * BUFBYTES + aoffs[mh * 4 + mm];
      aq[mm * 2 + 0] = *reinterpret_cast<const bf16x8*>(lds + off);
      aq[mm * 2 + 1] = *reinterpret_cast<const bf16x8*>(lds + (off ^ 64));
    }
  };
  auto READ_B = [&](int q, int nh, bf16x8* dst) {
#pragma unroll
    for (int nn = 0; nn < 2; ++nn) {
      int off = q * BUFBYTES + OPBYTES + boffs[nh * 2 + nn];
      dst[nn * 2 + 0] = *reinterpret_cast<const bf16x8*>(lds + off);
      dst[nn * 2 + 1] = *reinterpret_cast<const bf16x8*>(lds + (off ^ 64));
    }
  };
  auto MMA = [&](int mh, int nh, const bf16x8* bb) {
    __builtin_amdgcn_s_setprio(1);
#pragma unroll
    for (int mm = 0; mm < 4; ++mm)
#pragma unroll
      for (int nn = 0; nn < 2; ++nn)
#pragma unroll
        for (int kk = 0; kk < 2; ++kk)
          acc[mh * 4 + mm][nh * 2 + nn] = __builtin_amdgcn_mfma_f32_16x16x32_bf16(
              aq[mm * 2 + kk], bb[nn * 2 + kk], acc[mh * 4 + mm][nh * 2 + nn],
              0, 0, 0);
    __builtin_amdgcn_s_setprio(0);
  };

  // Prologue: buf0 <- tile0 (B0,B1,A0,A1), buf1 <- tile1 B halves.
  STAGE_B(0, 0, 0);
  STAGE_B(1, 0, 0);
  STAGE_A(0, 0, 0);
  STAGE_A(1, 0, 0);
  STAGE_B(0, 1, 1);
  STAGE_B(1, 1, 1);
  VM4();  // retire buf0's 8 (tile0 complete); retain b1.B0/B1 in flight
  BARRIER();

  const int np = nt >> 1;
  // Main loop: np-1 iterations, all stages unconditional (exact ledger).
  for (int p = 0; p < np - 1; ++p) {
    const int t0 = 2 * p, t1 = t0 + 1;
    // ph1: buf0 quad (m-lo, n-lo)
    READ_A(0, 0);
    READ_B(0, 0, blo);
    STAGE_A(0, t1, 1);
    BARRIER(); LGKM0();
    MMA(0, 0, blo);
    BARRIER();
    // ph2: (m-lo, n-hi)
    READ_B(0, 1, bhi);
    STAGE_A(1, t1, 1);
    BARRIER(); LGKM0();
    MMA(0, 1, bhi);
    BARRIER();
    // ph3: (m-hi, n-hi)
    READ_A(0, 1);
    STAGE_B(0, t0 + 2, 0);
    BARRIER(); LGKM0();
    MMA(1, 1, bhi);
    BARRIER();
    // ph4: (m-hi, n-lo) — counted vmcnt: retires ALL of buf1 tile t1
    STAGE_B(1, t0 + 2, 0);
    BARRIER();
    MMA(1, 0, blo);
    VM4();
    BARRIER();
    // ph5: buf1 quad (m-lo, n-lo)
    READ_A(1, 0);
    READ_B(1, 0, blo);
    STAGE_A(0, t0 + 2, 0);
    BARRIER(); LGKM0();
    MMA(0, 0, blo);
    BARRIER();
    // ph6
    READ_B(1, 1, bhi);
    STAGE_A(1, t0 + 2, 0);
    BARRIER(); LGKM0();
    MMA(0, 1, bhi);
    BARRIER();
    // ph7
    READ_A(1, 1);
    STAGE_B(0, t1 + 2, 1);
    BARRIER(); LGKM0();
    MMA(1, 1, bhi);
    BARRIER();
    // ph8 — counted vmcnt: retires ALL of buf0 tile t0+2
    STAGE_B(1, t1 + 2, 1);
    BARRIER();
    MMA(1, 0, blo);
    VM4();
    BARRIER();
  }

  // Peeled final iteration (t0 = nt-2, t1 = nt-1): only b1.A stages remain;
  // full drain at ph4 so ph5/ph7's ds_reads of buf1.A are covered.
  {
    const int t1 = nt - 1;
    // ph1
    READ_A(0, 0);
    READ_B(0, 0, blo);
    STAGE_A(0, t1, 1);
    BARRIER(); LGKM0();
    MMA(0, 0, blo);
    BARRIER();
    // ph2
    READ_B(0, 1, bhi);
    STAGE_A(1, t1, 1);
    BARRIER(); LGKM0();
    MMA(0, 1, bhi);
    BARRIER();
    // ph3
    READ_A(0, 1);
    BARRIER(); LGKM0();
    MMA(1, 1, bhi);
    BARRIER();
    // ph4 — FULL drain (b1.B already landed; b1.A0/A1 must land before ph5/ph7)
    BARRIER();
    MMA(1, 0, blo);
    VM0();
    BARRIER();
    // ph5
    READ_A(1, 0);
    READ_B(1, 0, blo);
    BARRIER(); LGKM0();
    MMA(0, 0, blo);
    BARRIER();
    // ph6
    READ_B(1, 1, bhi);
    BARRIER(); LGKM0();
    MMA(0, 1, bhi);
    BARRIER();
    // ph7
    READ_A(1, 1);
    BARRIER(); LGKM0();
    MMA(1, 1, bhi);
    BARRIER();
    // ph8
    MMA(1, 0, blo);
  }

  // Epilogue: C/D layout col=lane&15, row=(lane>>4)*4+reg  [m89/m91]
  // Agent-scope stores (replay-safe visibility past per-XCD L2).
  const int cn = lane & 15;
  const int r4 = (lane >> 4) << 2;
#pragma unroll
  for (int n = 0; n < 4; ++n) {
    const int gcol = bcol + wn * 64 + n * 16 + cn;
    const float bv = bias[gcol];
#pragma unroll
    for (int m = 0; m < 8; ++m) {
      const int grow = brow + wm * 128 + m * 16 + r4;
      float* outp = C + (size_t)grow * N + gcol;
#pragma unroll
      for (int j = 0; j < 4; ++j) {
        float v = acc[m][n][j] + bv;
        __hip_atomic_store(outp + (size_t)j * N, v, __ATOMIC_RELAXED,
                           __HIP_MEMORY_SCOPE_AGENT);
      }
    }
  }
}

extern "C" void kernel_launch(void* const* d_in, const int* in_sizes, int n_in,
                              void* d_out, int out_size, void* d_ws, size_t ws_size,
                              hipStream_t stream) {
  const float* x = (const float*)d_in[0];
  const float* W = (const float*)d_in[1];
  const float* b = (const float*)d_in[2];
  float* out = (float*)d_out;

  const int N = in_sizes[2];       // D_OUT
  const int K = in_sizes[1] / N;   // D_IN
  const int M = in_sizes[0] / K;   // B rows

  const size_t needA = (size_t)M * K * sizeof(bf16_t);
  const size_t needB = (size_t)N * K * sizeof(bf16_t);
  const bool tiled_ok = (M % BM == 0) && (N % BN == 0) && (K % (2 * BK) == 0) &&
                        (K / BK >= 2) && (ws_size >= needA + needB);
  if (!tiled_ok) {
    dim3 g((unsigned)((N + 255) / 256), (unsigned)M);
    naive_kernel<<<g, 256, 0, stream>>>(x, W, b, out, M, N, K);
    return;
  }

  bf16_t* qA = (bf16_t*)d_ws;
  bf16_t* qB = qA + (size_t)M * K;
  const long axn8 = (long)M * K / 8;
  const long totn8 = axn8 + (long)N * K / 8;
  quant2_bf16_kernel<<<2048, 256, 0, stream>>>(x, W, qA, axn8, totn8);

  (void)hipFuncSetAttribute((const void*)gemm_bt_bf16,
                            hipFuncAttributeMaxDynamicSharedMemorySize, LDS_TOTAL);

  const int nwg = (M / BM) * (N / BN);
  gemm_bt_bf16<<<nwg, THREADS, LDS_TOTAL, stream>>>(qA, qB, b, out, M, N, K);
}

// Round 7
// 162.941 us; speedup vs baseline: 1.0256x; 1.0256x over previous
//
#include <hip/hip_runtime.h>
#include <hip/hip_bf16.h>
#include <stdint.h>

typedef __hip_bfloat16 bf16_t;
typedef __attribute__((ext_vector_type(8))) __bf16 bf16x8;
typedef __attribute__((ext_vector_type(4))) float f32x4;
typedef __attribute__((ext_vector_type(8))) unsigned short ushort8;
typedef __attribute__((ext_vector_type(2))) unsigned long long u64x2;

#define BM 256
#define BN 256
#define BK 64
#define THREADS 512
#define OPBYTES 32768   // one operand per buf: 256 rows x 128 B
#define BUFBYTES 65536  // A + B
#define LDS_TOTAL 131072

// ---------------- fused quantize: q = rint(v*100)/100, cast to bf16 ----------------
__global__ __launch_bounds__(256) void quant2_bf16_kernel(
    const float* __restrict__ x, const float* __restrict__ w,
    bf16_t* __restrict__ q, long axn8, long totn8) {
  long idx = (long)blockIdx.x * blockDim.x + threadIdx.x;
  long stride = (long)gridDim.x * blockDim.x;
  for (long i = idx; i < totn8; i += stride) {
    const float* src = (i < axn8) ? (x + i * 8) : (w + (i - axn8) * 8);
    const float4* p = reinterpret_cast<const float4*>(src);
    float4 v0 = p[0];
    float4 v1 = p[1];
    float vv[8] = {v0.x, v0.y, v0.z, v0.w, v1.x, v1.y, v1.z, v1.w};
    ushort8 r;
#pragma unroll
    for (int j = 0; j < 8; ++j) {
      float qq = rintf(vv[j] * 100.0f) / 100.0f;  // half-to-even, matches jnp.round
      __hip_bfloat16 h = __float2bfloat16(qq);
      r[j] = __builtin_bit_cast(unsigned short, h);
    }
    u64x2 u = __builtin_bit_cast(u64x2, r);
    unsigned long long* dst = reinterpret_cast<unsigned long long*>(q + i * 8);
    __hip_atomic_store(dst + 0, u[0], __ATOMIC_RELAXED, __HIP_MEMORY_SCOPE_AGENT);
    __hip_atomic_store(dst + 1, u[1], __ATOMIC_RELAXED, __HIP_MEMORY_SCOPE_AGENT);
  }
}

// ---------------- fallback ----------------
__global__ void naive_kernel(const float* __restrict__ x, const float* __restrict__ W,
                             const float* __restrict__ b, float* __restrict__ out,
                             int M, int N, int K) {
  int o = blockIdx.x * blockDim.x + threadIdx.x;
  int m = blockIdx.y;
  if (o >= N || m >= M) return;
  float s = 0.f;
  for (int k = 0; k < K; ++k) {
    float qx = rintf(x[(size_t)m * K + k] * 100.f) / 100.f;
    float qw = rintf(W[(size_t)o * K + k] * 100.f) / 100.f;
    s += qx * qw;
  }
  float v = s + b[o];
  __hip_atomic_store(out + (size_t)m * N + o, v, __ATOMIC_RELAXED,
                     __HIP_MEMORY_SCOPE_AGENT);
}

__device__ __forceinline__ void gload_lds16(const bf16_t* g, const char* l) {
  __builtin_amdgcn_global_load_lds(
      (const __attribute__((address_space(1))) unsigned int*)g,
      (__attribute__((address_space(3))) unsigned int*)l, 16, 0, 0);
}

#define BARRIER()                               \
  do {                                          \
    asm volatile("" ::: "memory");              \
    __builtin_amdgcn_s_barrier();               \
    asm volatile("" ::: "memory");              \
  } while (0)
#define LGKM0() asm volatile("s_waitcnt lgkmcnt(0)" ::: "memory")
#define VM8() asm volatile("s_waitcnt vmcnt(8)" ::: "memory")
#define VM0() asm volatile("s_waitcnt vmcnt(0)" ::: "memory")

// ---------------- bf16 GEMM, B^T input: C[m][n] = sum_k A[m][k]*B[n][k] + bias[n]
// 8-phase, ONE barrier per phase (at phase end), deep-prefetch stages.
// BM=BN=256, BK=64, 8 waves (2x4; each 128x64 out), 2 LDS K-tile buffers.
//
// Phase p = { STAGE (if any); ds_read this phase's frags; LGKM0; MMA quadrant;
//             VM8 (ph4/ph8 only); s_barrier }.
//
// Stage schedule (each STAGE_* = 2 loads; 16 loads/iter):
//   ph3: b0.B0',B1'(t0+2)  ph4: b0.A0',A1'(t0+2)
//   ph7: b1.B0'',B1''(t1+2) ph8: b1.A0'',A1''(t1+2)
// WAR proof (holds under any wave skew; 1 barrier/phase):
//   reads of a region complete at that phase's LGKM0 (< its barrier); the
//   overwriting STAGE issues after that barrier: b0.B last read ph2 -> staged
//   ph3; b0.A last read ph3 -> ph4; b1.B last read ph6 -> ph7; b1.A last read
//   ph7 -> ph8.
// vmcnt ledger (per wave, oldest-first): carried into iter = 8 (b1 tile t1,
//   staged prev ph7/ph8). ph4: outstanding 8+8 -> VM8 retires the carried 8
//   (b1 t1 landed; needed ph5) - those loads are 4-6 phases old => ~no stall.
//   ph8: outstanding 8+8 -> VM8 retires ph3/ph4's 8 (b0 t0+2; needed next ph1),
//   4-5 phases old. Last iteration PEELED: no stages; VM0 at ph4.
// No BAR1: waves may skew within a phase -> one wave's ds_reads overlap
// SIMD-mates' MFMAs (cross-wave LDS/matrix pipe overlap); setprio arbitrates.
// LDS swizzle: 128B rows, stored slot = slot ^ (row&7) (involution; 2 lanes/bank
// on ds_read_b128 = free per m136; measured 0 conflicts). global_load_lds dest
// linear (base+lane*16); swizzle applied on the global SOURCE (rule #21).
__global__ __launch_bounds__(THREADS, 2) void gemm_bt_bf16(
    const bf16_t* __restrict__ A,   // [M][K]
    const bf16_t* __restrict__ B,   // [N][K]
    const float* __restrict__ bias, // [N]
    float* __restrict__ C,          // [M][N]
    int M, int N, int K) {
  extern __shared__ char lds[];

  const int tid = threadIdx.x;
  const int lane = tid & 63;
  const int wave = tid >> 6;  // 0..7
  const int wm = wave >> 2;   // 0..1 -> output rows wm*128..+128
  const int wn = wave & 3;    // 0..3 -> output cols wn*64..+64
  const int lr = lane & 15;
  const int lg = lane >> 4;

  // XCD-aware bijective swizzle (nwg % 8 == 0 guaranteed by tiled_ok)
  int nbn = N / BN;
  int nwg = gridDim.x;
  int bid = blockIdx.x;
  int swz = bid;
  if ((nwg & 7) == 0) {
    int cpx = nwg >> 3;
    swz = (bid & 7) * cpx + (bid >> 3);
  }
  const int brow = (swz / nbn) * BM;
  const int bcol = (swz % nbn) * BN;

  // ds_read byte offsets within an operand region (kk=0; kk=1 is ^64)
  int aoffs[8], boffs[4];
#pragma unroll
  for (int m = 0; m < 8; ++m) {
    int r = wm * 128 + m * 16 + lr;
    aoffs[m] = r * 128 + (((lg) ^ (r & 7)) << 4);
  }
#pragma unroll
  for (int n = 0; n < 4; ++n) {
    int r = wn * 64 + n * 16 + lr;
    boffs[n] = r * 128 + (((lg) ^ (r & 7)) << 4);
  }

  f32x4 acc[8][4];
#pragma unroll
  for (int m = 0; m < 8; ++m)
#pragma unroll
    for (int n = 0; n < 4; ++n) acc[m][n] = (f32x4){0.f, 0.f, 0.f, 0.f};

  const int nt = K / BK;

  auto STAGE_A = [&](int h, int kt, int q) {
#pragma unroll
    for (int i = 0; i < 2; ++i) {
      int row = h * 128 + i * 64 + (tid >> 3);
      int L = q * BUFBYTES + row * 128 + ((tid & 7) << 4);
      int slot = (tid & 7) ^ (row & 7);
      gload_lds16(A + (size_t)(brow + row) * K + (size_t)kt * 64 + slot * 8,
                  lds + L);
    }
  };
  auto STAGE_B = [&](int h, int kt, int q) {
#pragma unroll
    for (int i = 0; i < 2; ++i) {
      int row = h * 128 + i * 64 + (tid >> 3);
      int L = q * BUFBYTES + OPBYTES + row * 128 + ((tid & 7) << 4);
      int slot = (tid & 7) ^ (row & 7);
      gload_lds16(B + (size_t)(bcol + row) * K + (size_t)kt * 64 + slot * 8,
                  lds + L);
    }
  };

  bf16x8 aq[8], blo[4], bhi[4];  // A quadrant [mm][kk]; B quadrants [nn][kk]
  auto READ_A = [&](int q, int mh) {
#pragma unroll
    for (int mm = 0; mm < 4; ++mm) {
      int off = q * BUFBYTES + aoffs[mh * 4 + mm];
      aq[mm * 2 + 0] = *reinterpret_cast<const bf16x8*>(lds + off);
      aq[mm * 2 + 1] = *reinterpret_cast<const bf16x8*>(lds + (off ^ 64));
    }
  };
  auto READ_B = [&](int q, int nh, bf16x8* dst) {
#pragma unroll
    for (int nn = 0; nn < 2; ++nn) {
      int off = q * BUFBYTES + OPBYTES + boffs[nh * 2 + nn];
      dst[nn * 2 + 0] = *reinterpret_cast<const bf16x8*>(lds + off);
      dst[nn * 2 + 1] = *reinterpret_cast<const bf16x8*>(lds + (off ^ 64));
    }
  };
  auto MMA = [&](int mh, int nh, const bf16x8* bb) {
    __builtin_amdgcn_s_setprio(1);
#pragma unroll
    for (int mm = 0; mm < 4; ++mm)
#pragma unroll
      for (int nn = 0; nn < 2; ++nn)
#pragma unroll
        for (int kk = 0; kk < 2; ++kk)
          acc[mh * 4 + mm][nh * 2 + nn] = __builtin_amdgcn_mfma_f32_16x16x32_bf16(
              aq[mm * 2 + kk], bb[nn * 2 + kk], acc[mh * 4 + mm][nh * 2 + nn],
              0, 0, 0);
    __builtin_amdgcn_s_setprio(0);
  };

  // Prologue: both tiles fully staged; b0's 8 retired, b1's 8 carried in flight.
  STAGE_B(0, 0, 0); STAGE_B(1, 0, 0); STAGE_A(0, 0, 0); STAGE_A(1, 0, 0);
  STAGE_B(0, 1, 1); STAGE_B(1, 1, 1); STAGE_A(0, 1, 1); STAGE_A(1, 1, 1);
  VM8();
  BARRIER();

  const int np = nt >> 1;
  for (int p = 0; p < np - 1; ++p) {
    const int t2 = 2 * p + 2, t3 = 2 * p + 3;
    // ph1: buf0 quad (m-lo, n-lo)
    READ_A(0, 0); READ_B(0, 0, blo);
    LGKM0();
    MMA(0, 0, blo);
    BARRIER();
    // ph2: (m-lo, n-hi)
    READ_B(0, 1, bhi);
    LGKM0();
    MMA(0, 1, bhi);
    BARRIER();
    // ph3: (m-hi, n-hi); stage b0.B(t2) (b0.B last read ph2)
    STAGE_B(0, t2, 0); STAGE_B(1, t2, 0);
    READ_A(0, 1);
    LGKM0();
    MMA(1, 1, bhi);
    BARRIER();
    // ph4: (m-hi, n-lo); stage b0.A(t2) (b0.A last read ph3); retire b1(t1)
    STAGE_A(0, t2, 0); STAGE_A(1, t2, 0);
    MMA(1, 0, blo);
    VM8();
    BARRIER();
    // ph5: buf1 quad (m-lo, n-lo)
    READ_A(1, 0); READ_B(1, 0, blo);
    LGKM0();
    MMA(0, 0, blo);
    BARRIER();
    // ph6
    READ_B(1, 1, bhi);
    LGKM0();
    MMA(0, 1, bhi);
    BARRIER();
    // ph7: stage b1.B(t3) (b1.B last read ph6)
    STAGE_B(0, t3, 1); STAGE_B(1, t3, 1);
    READ_A(1, 1);
    LGKM0();
    MMA(1, 1, bhi);
    BARRIER();
    // ph8: stage b1.A(t3) (b1.A last read ph7); retire b0(t2)
    STAGE_A(0, t3, 1); STAGE_A(1, t3, 1);
    MMA(1, 0, blo);
    VM8();
    BARRIER();
  }

  // Peeled final iteration: no stages; full drain of carried b1 loads at ph4.
  {
    READ_A(0, 0); READ_B(0, 0, blo);
    LGKM0();
    MMA(0, 0, blo);
    BARRIER();
    READ_B(0, 1, bhi);
    LGKM0();
    MMA(0, 1, bhi);
    BARRIER();
    READ_A(0, 1);
    LGKM0();
    MMA(1, 1, bhi);
    BARRIER();
    MMA(1, 0, blo);
    VM0();
    BARRIER();
    READ_A(1, 0); READ_B(1, 0, blo);
    LGKM0();
    MMA(0, 0, blo);
    BARRIER();
    READ_B(1, 1, bhi);
    LGKM0();
    MMA(0, 1, bhi);
    BARRIER();
    READ_A(1, 1);
    LGKM0();
    MMA(1, 1, bhi);
    BARRIER();
    MMA(1, 0, blo);
  }

  // Epilogue: C/D layout col=lane&15, row=(lane>>4)*4+reg  [m89/m91]
  // Agent-scope stores (replay-safe visibility past per-XCD L2).
  const int cn = lane & 15;
  const int r4 = (lane >> 4) << 2;
#pragma unroll
  for (int n = 0; n < 4; ++n) {
    const int gcol = bcol + wn * 64 + n * 16 + cn;
    const float bv = bias[gcol];
#pragma unroll
    for (int m = 0; m < 8; ++m) {
      const int grow = brow + wm * 128 + m * 16 + r4;
      float* outp = C + (size_t)grow * N + gcol;
#pragma unroll
      for (int j = 0; j < 4; ++j) {
        float v = acc[m][n][j] + bv;
        __hip_atomic_store(outp + (size_t)j * N, v, __ATOMIC_RELAXED,
                           __HIP_MEMORY_SCOPE_AGENT);
      }
    }
  }
}

extern "C" void kernel_launch(void* const* d_in, const int* in_sizes, int n_in,
                              void* d_out, int out_size, void* d_ws, size_t ws_size,
                              hipStream_t stream) {
  const float* x = (const float*)d_in[0];
  const float* W = (const float*)d_in[1];
  const float* b = (const float*)d_in[2];
  float* out = (float*)d_out;

  const int N = in_sizes[2];       // D_OUT
  const int K = in_sizes[1] / N;   // D_IN
  const int M = in_sizes[0] / K;   // B rows

  const size_t needA = (size_t)M * K * sizeof(bf16_t);
  const size_t needB = (size_t)N * K * sizeof(bf16_t);
  const bool tiled_ok = (M % BM == 0) && (N % BN == 0) && (K % (2 * BK) == 0) &&
                        (K / BK >= 2) && (ws_size >= needA + needB);
  if (!tiled_ok) {
    dim3 g((unsigned)((N + 255) / 256), (unsigned)M);
    naive_kernel<<<g, 256, 0, stream>>>(x, W, b, out, M, N, K);
    return;
  }

  bf16_t* qA = (bf16_t*)d_ws;
  bf16_t* qB = qA + (size_t)M * K;
  const long axn8 = (long)M * K / 8;
  const long totn8 = axn8 + (long)N * K / 8;
  quant2_bf16_kernel<<<2048, 256, 0, stream>>>(x, W, qA, axn8, totn8);

  (void)hipFuncSetAttribute((const void*)gemm_bt_bf16,
                            hipFuncAttributeMaxDynamicSharedMemorySize, LDS_TOTAL);

  const int nwg = (M / BM) * (N / BN);
  gemm_bt_bf16<<<nwg, THREADS, LDS_TOTAL, stream>>>(qA, qB, b, out, M, N, K);
}

// Round 8
// 160.231 us; speedup vs baseline: 1.0429x; 1.0169x over previous
//
#include <hip/hip_runtime.h>
#include <hip/hip_bf16.h>
#include <stdint.h>

typedef __hip_bfloat16 bf16_t;
typedef __attribute__((ext_vector_type(8))) __bf16 bf16x8;
typedef __attribute__((ext_vector_type(4))) float f32x4;
typedef __attribute__((ext_vector_type(8))) unsigned short ushort8;
typedef __attribute__((ext_vector_type(2))) unsigned long long u64x2;

#define BM 256
#define BN 256
#define BK 64
#define THREADS 512
#define OPBYTES 32768   // one operand per buf: 256 rows x 128 B
#define BUFBYTES 65536  // A + B
#define LDS_TOTAL 131072

// ---------------- fused quantize: q = rint(v*100)/100, cast to bf16 ----------------
__global__ __launch_bounds__(256) void quant2_bf16_kernel(
    const float* __restrict__ x, const float* __restrict__ w,
    bf16_t* __restrict__ q, long axn8, long totn8) {
  long idx = (long)blockIdx.x * blockDim.x + threadIdx.x;
  long stride = (long)gridDim.x * blockDim.x;
  for (long i = idx; i < totn8; i += stride) {
    const float* src = (i < axn8) ? (x + i * 8) : (w + (i - axn8) * 8);
    const float4* p = reinterpret_cast<const float4*>(src);
    float4 v0 = p[0];
    float4 v1 = p[1];
    float vv[8] = {v0.x, v0.y, v0.z, v0.w, v1.x, v1.y, v1.z, v1.w};
    ushort8 r;
#pragma unroll
    for (int j = 0; j < 8; ++j) {
      float qq = rintf(vv[j] * 100.0f) / 100.0f;  // half-to-even, matches jnp.round
      __hip_bfloat16 h = __float2bfloat16(qq);
      r[j] = __builtin_bit_cast(unsigned short, h);
    }
    u64x2 u = __builtin_bit_cast(u64x2, r);
    unsigned long long* dst = reinterpret_cast<unsigned long long*>(q + i * 8);
    __hip_atomic_store(dst + 0, u[0], __ATOMIC_RELAXED, __HIP_MEMORY_SCOPE_AGENT);
    __hip_atomic_store(dst + 1, u[1], __ATOMIC_RELAXED, __HIP_MEMORY_SCOPE_AGENT);
  }
}

// ---------------- fallback ----------------
__global__ void naive_kernel(const float* __restrict__ x, const float* __restrict__ W,
                             const float* __restrict__ b, float* __restrict__ out,
                             int M, int N, int K) {
  int o = blockIdx.x * blockDim.x + threadIdx.x;
  int m = blockIdx.y;
  if (o >= N || m >= M) return;
  float s = 0.f;
  for (int k = 0; k < K; ++k) {
    float qx = rintf(x[(size_t)m * K + k] * 100.f) / 100.f;
    float qw = rintf(W[(size_t)o * K + k] * 100.f) / 100.f;
    s += qx * qw;
  }
  float v = s + b[o];
  __hip_atomic_store(out + (size_t)m * N + o, v, __ATOMIC_RELAXED,
                     __HIP_MEMORY_SCOPE_AGENT);
}

__device__ __forceinline__ void gload_lds16(const bf16_t* g, const char* l) {
  __builtin_amdgcn_global_load_lds(
      (const __attribute__((address_space(1))) unsigned int*)g,
      (__attribute__((address_space(3))) unsigned int*)l, 16, 0, 0);
}

#define BARRIER()                               \
  do {                                          \
    asm volatile("" ::: "memory");              \
    __builtin_amdgcn_s_barrier();               \
    asm volatile("" ::: "memory");              \
  } while (0)
#define VM8() asm volatile("s_waitcnt vmcnt(8)" ::: "memory")
#define VM0() asm volatile("s_waitcnt vmcnt(0)" ::: "memory")

// ---------------- bf16 GEMM, B^T input: C[m][n] = sum_k A[m][k]*B[n][k] + bias[n]
// 8-phase, ONE barrier per phase, deep-prefetch stages, NO explicit lgkmcnt:
// the ds_reads are plain ext_vector loads, so the compiler emits fine-grained
// counted lgkmcnt between each read and its consumer MFMA (m97 asm evidence),
// letting LDS reads overlap MFMA issue within a wave. Round-7 PMC showed the
// old per-phase lgkmcnt(0) serialized the two pipes exactly (9447 cyc/iter =
// 4966 MFMA + 4608 ds_read).
//
// WAR safety WITHOUT lgkmcnt(0): every ds_read in a phase feeds an MFMA in the
// SAME phase (ph1: blo+aq -> MMA(0,0); ph2: bhi -> MMA(0,1); ph3: aq -> MMA(1,1)),
// so the compiler's implicit waits drain all reads before the wave reaches the
// phase-end barrier (DS ops complete in order per wave). No phase stages and
// reads the same region. The overwriting STAGE issues >=1 barrier after the
// region's last read phase: b0.B last read ph2 -> staged ph3; b0.A ph3 -> ph4;
// b1.B ph6 -> ph7; b1.A ph7 -> ph8.
// vmcnt ledger (per wave, oldest-first): carried into iter = 8 (b1 t1, staged
//   prev ph7/ph8). ph4: 8+8 outstanding -> VM8 retires the carried 8 (needed
//   ph5), 4-6 phases old => ~no stall. ph8: VM8 retires ph3/ph4's 8 (b0 t0+2,
//   needed next ph1). LAST iteration PEELED: no stages; VM0 at ph4.
// LDS swizzle: 128B rows, stored slot = slot ^ (row&7) (involution; 2 lanes/bank
// on ds_read_b128 = free per m136; measured 0 conflicts). global_load_lds dest
// linear (base+lane*16); swizzle applied on the global SOURCE (rule #21).
__global__ __launch_bounds__(THREADS, 2) void gemm_bt_bf16(
    const bf16_t* __restrict__ A,   // [M][K]
    const bf16_t* __restrict__ B,   // [N][K]
    const float* __restrict__ bias, // [N]
    float* __restrict__ C,          // [M][N]
    int M, int N, int K) {
  extern __shared__ char lds[];

  const int tid = threadIdx.x;
  const int lane = tid & 63;
  const int wave = tid >> 6;  // 0..7
  const int wm = wave >> 2;   // 0..1 -> output rows wm*128..+128
  const int wn = wave & 3;    // 0..3 -> output cols wn*64..+64
  const int lr = lane & 15;
  const int lg = lane >> 4;

  // XCD-aware bijective swizzle (nwg % 8 == 0 guaranteed by tiled_ok)
  int nbn = N / BN;
  int nwg = gridDim.x;
  int bid = blockIdx.x;
  int swz = bid;
  if ((nwg & 7) == 0) {
    int cpx = nwg >> 3;
    swz = (bid & 7) * cpx + (bid >> 3);
  }
  const int brow = (swz / nbn) * BM;
  const int bcol = (swz % nbn) * BN;

  // ds_read byte offsets within an operand region (kk=0; kk=1 is ^64)
  int aoffs[8], boffs[4];
#pragma unroll
  for (int m = 0; m < 8; ++m) {
    int r = wm * 128 + m * 16 + lr;
    aoffs[m] = r * 128 + (((lg) ^ (r & 7)) << 4);
  }
#pragma unroll
  for (int n = 0; n < 4; ++n) {
    int r = wn * 64 + n * 16 + lr;
    boffs[n] = r * 128 + (((lg) ^ (r & 7)) << 4);
  }

  f32x4 acc[8][4];
#pragma unroll
  for (int m = 0; m < 8; ++m)
#pragma unroll
    for (int n = 0; n < 4; ++n) acc[m][n] = (f32x4){0.f, 0.f, 0.f, 0.f};

  const int nt = K / BK;

  auto STAGE_A = [&](int h, int kt, int q) {
#pragma unroll
    for (int i = 0; i < 2; ++i) {
      int row = h * 128 + i * 64 + (tid >> 3);
      int L = q * BUFBYTES + row * 128 + ((tid & 7) << 4);
      int slot = (tid & 7) ^ (row & 7);
      gload_lds16(A + (size_t)(brow + row) * K + (size_t)kt * 64 + slot * 8,
                  lds + L);
    }
  };
  auto STAGE_B = [&](int h, int kt, int q) {
#pragma unroll
    for (int i = 0; i < 2; ++i) {
      int row = h * 128 + i * 64 + (tid >> 3);
      int L = q * BUFBYTES + OPBYTES + row * 128 + ((tid & 7) << 4);
      int slot = (tid & 7) ^ (row & 7);
      gload_lds16(B + (size_t)(bcol + row) * K + (size_t)kt * 64 + slot * 8,
                  lds + L);
    }
  };

  bf16x8 aq[8], blo[4], bhi[4];  // A quadrant [mm][kk]; B quadrants [nn][kk]
  auto READ_A = [&](int q, int mh) {
#pragma unroll
    for (int mm = 0; mm < 4; ++mm) {
      int off = q * BUFBYTES + aoffs[mh * 4 + mm];
      aq[mm * 2 + 0] = *reinterpret_cast<const bf16x8*>(lds + off);
      aq[mm * 2 + 1] = *reinterpret_cast<const bf16x8*>(lds + (off ^ 64));
    }
  };
  auto READ_B = [&](int q, int nh, bf16x8* dst) {
#pragma unroll
    for (int nn = 0; nn < 2; ++nn) {
      int off = q * BUFBYTES + OPBYTES + boffs[nh * 2 + nn];
      dst[nn * 2 + 0] = *reinterpret_cast<const bf16x8*>(lds + off);
      dst[nn * 2 + 1] = *reinterpret_cast<const bf16x8*>(lds + (off ^ 64));
    }
  };
  auto MMA = [&](int mh, int nh, const bf16x8* bb) {
    __builtin_amdgcn_s_setprio(1);
#pragma unroll
    for (int mm = 0; mm < 4; ++mm)
#pragma unroll
      for (int nn = 0; nn < 2; ++nn)
#pragma unroll
        for (int kk = 0; kk < 2; ++kk)
          acc[mh * 4 + mm][nh * 2 + nn] = __builtin_amdgcn_mfma_f32_16x16x32_bf16(
              aq[mm * 2 + kk], bb[nn * 2 + kk], acc[mh * 4 + mm][nh * 2 + nn],
              0, 0, 0);
    __builtin_amdgcn_s_setprio(0);
  };

  // Prologue: both tiles fully staged; b0's 8 retired, b1's 8 carried in flight.
  STAGE_B(0, 0, 0); STAGE_B(1, 0, 0); STAGE_A(0, 0, 0); STAGE_A(1, 0, 0);
  STAGE_B(0, 1, 1); STAGE_B(1, 1, 1); STAGE_A(0, 1, 1); STAGE_A(1, 1, 1);
  VM8();
  BARRIER();

  const int np = nt >> 1;
  for (int p = 0; p < np - 1; ++p) {
    const int t2 = 2 * p + 2, t3 = 2 * p + 3;
    // ph1: buf0 quad (m-lo, n-lo). B first so the first MFMA's operands land early.
    READ_B(0, 0, blo); READ_A(0, 0);
    MMA(0, 0, blo);
    BARRIER();
    // ph2: (m-lo, n-hi)
    READ_B(0, 1, bhi);
    MMA(0, 1, bhi);
    BARRIER();
    // ph3: (m-hi, n-hi); stage b0.B(t2) (b0.B last read ph2)
    STAGE_B(0, t2, 0); STAGE_B(1, t2, 0);
    READ_A(0, 1);
    MMA(1, 1, bhi);
    BARRIER();
    // ph4: (m-hi, n-lo); stage b0.A(t2) (b0.A last read ph3); retire b1(t1)
    STAGE_A(0, t2, 0); STAGE_A(1, t2, 0);
    MMA(1, 0, blo);
    VM8();
    BARRIER();
    // ph5: buf1 quad (m-lo, n-lo)
    READ_B(1, 0, blo); READ_A(1, 0);
    MMA(0, 0, blo);
    BARRIER();
    // ph6
    READ_B(1, 1, bhi);
    MMA(0, 1, bhi);
    BARRIER();
    // ph7: stage b1.B(t3) (b1.B last read ph6)
    STAGE_B(0, t3, 1); STAGE_B(1, t3, 1);
    READ_A(1, 1);
    MMA(1, 1, bhi);
    BARRIER();
    // ph8: stage b1.A(t3) (b1.A last read ph7); retire b0(t2)
    STAGE_A(0, t3, 1); STAGE_A(1, t3, 1);
    MMA(1, 0, blo);
    VM8();
    BARRIER();
  }

  // Peeled final iteration: no stages; full drain of carried b1 loads at ph4.
  {
    READ_B(0, 0, blo); READ_A(0, 0);
    MMA(0, 0, blo);
    BARRIER();
    READ_B(0, 1, bhi);
    MMA(0, 1, bhi);
    BARRIER();
    READ_A(0, 1);
    MMA(1, 1, bhi);
    BARRIER();
    MMA(1, 0, blo);
    VM0();
    BARRIER();
    READ_B(1, 0, blo); READ_A(1, 0);
    MMA(0, 0, blo);
    BARRIER();
    READ_B(1, 1, bhi);
    MMA(0, 1, bhi);
    BARRIER();
    READ_A(1, 1);
    MMA(1, 1, bhi);
    BARRIER();
    MMA(1, 0, blo);
  }

  // Epilogue: C/D layout col=lane&15, row=(lane>>4)*4+reg  [m89/m91]
  // Agent-scope stores (replay-safe visibility past per-XCD L2).
  const int cn = lane & 15;
  const int r4 = (lane >> 4) << 2;
#pragma unroll
  for (int n = 0; n < 4; ++n) {
    const int gcol = bcol + wn * 64 + n * 16 + cn;
    const float bv = bias[gcol];
#pragma unroll
    for (int m = 0; m < 8; ++m) {
      const int grow = brow + wm * 128 + m * 16 + r4;
      float* outp = C + (size_t)grow * N + gcol;
#pragma unroll
      for (int j = 0; j < 4; ++j) {
        float v = acc[m][n][j] + bv;
        __hip_atomic_store(outp + (size_t)j * N, v, __ATOMIC_RELAXED,
                           __HIP_MEMORY_SCOPE_AGENT);
      }
    }
  }
}

extern "C" void kernel_launch(void* const* d_in, const int* in_sizes, int n_in,
                              void* d_out, int out_size, void* d_ws, size_t ws_size,
                              hipStream_t stream) {
  const float* x = (const float*)d_in[0];
  const float* W = (const float*)d_in[1];
  const float* b = (const float*)d_in[2];
  float* out = (float*)d_out;

  const int N = in_sizes[2];       // D_OUT
  const int K = in_sizes[1] / N;   // D_IN
  const int M = in_sizes[0] / K;   // B rows

  const size_t needA = (size_t)M * K * sizeof(bf16_t);
  const size_t needB = (size_t)N * K * sizeof(bf16_t);
  const bool tiled_ok = (M % BM == 0) && (N % BN == 0) && (K % (2 * BK) == 0) &&
                        (K / BK >= 2) && (ws_size >= needA + needB);
  if (!tiled_ok) {
    dim3 g((unsigned)((N + 255) / 256), (unsigned)M);
    naive_kernel<<<g, 256, 0, stream>>>(x, W, b, out, M, N, K);
    return;
  }

  bf16_t* qA = (bf16_t*)d_ws;
  bf16_t* qB = qA + (size_t)M * K;
  const long axn8 = (long)M * K / 8;
  const long totn8 = axn8 + (long)N * K / 8;
  quant2_bf16_kernel<<<2048, 256, 0, stream>>>(x, W, qA, axn8, totn8);

  (void)hipFuncSetAttribute((const void*)gemm_bt_bf16,
                            hipFuncAttributeMaxDynamicSharedMemorySize, LDS_TOTAL);

  const int nwg = (M / BM) * (N / BN);
  gemm_bt_bf16<<<nwg, THREADS, LDS_TOTAL, stream>>>(qA, qB, b, out, M, N, K);
}